// Round 3
// baseline (307.423 us; speedup 1.0000x reference)
//
#include <hip/hip_runtime.h>

// ---------------------------------------------------------------------------
// CapsNet dynamic routing, fully fused, fp32.
//   x: [B=64, I=8192, N=8]   W: [I=8192, J=8, N=8, M=16]   out: [B, J=8, M=16]
//
// b_logits after t iters = dot(sum_{t'<=t} v_{t'}, u_hat); carry only
// vsum[B,J,M] between passes, recompute u_hat per pass (x,W are L3-resident).
//
// Pass kernel: 256 blocks x 1024 threads. Thread = (bq, j, mq, i-parity):
// owns b in {bq, bq+16, bq+32, bq+48}, one j, one m-quad.
//   KEY: one ds_read_b128 of W feeds 4 batches x 4 m x 8 n = 128 FMAs.
//   Round-2 layout read 512 B of W per (thread,i) for ONE b -> 2.15 GB LDS
//   traffic/pass = 27 us data floor (the measured 51 us pole). This layout
//   reads 128 B per (thread,i) serving 4 b's -> 537 MB -> ~7 us/CU floor.
// Softmax: partial m-dot per lane, shfl_xor 1,2 (mq lanes, DPP quad-perm)
// then j-softmax via xor 4,8,16; 4 independent chains (one per b) hide DS
// latency. |logit| << 10 -> no max-subtract needed.
// amdgpu_waves_per_eu(4,4): pin 4 waves/SIMD so the allocator targets 128
// VGPRs (round-2 build chose 64 and showed 42 MB of suspected scratch WRITE).
// Reduce kernel: coalesced 256-partial sum + squash; first call writes vsum.
// ---------------------------------------------------------------------------

#define BB      64
#define ICAPS   8192
#define NDIM    8
#define JCAPS   8
#define MDIM    16
#define NBLK    256
#define ICHUNK  (ICAPS / NBLK)        // 32
#define IG      8                     // i's staged per barrier
#define NSTAGE  (ICHUNK / IG)         // 4
#define WJ_STRIDE (NDIM * MDIM + 4)   // 132 floats: pad -> j-rows spread banks
#define WI_STRIDE (JCAPS * WJ_STRIDE) // 1056 floats per i
#define S_ELEMS  (BB * JCAPS * MDIM)  // 8192 floats per s / vsum / out

// MODE 0: uniform c = 1/8 (softmax of zero logits)
// MODE 1: c = softmax_j( dot(vsum[b,j,:], u_hat[b,i,j,:]) )
template <int MODE>
__global__ __launch_bounds__(1024)
__attribute__((amdgpu_waves_per_eu(4, 4)))
void caps_pass_kernel(
    const float* __restrict__ x, const float* __restrict__ W,
    const float* __restrict__ vsum, float* __restrict__ partial)
{
    __shared__ float Wlds[IG * WI_STRIDE];   // 33,792 B; reused for final reduce

    const int tid  = threadIdx.x;            // 0..1023
    const int mq   = tid & 3;                // m-quad (lane bits 0-1)
    const int j    = (tid >> 2) & 7;         // out-cap (lane bits 2-4)
    const int bq   = (tid >> 5) & 15;        // batch-quad base
    const int isub = tid >> 9;               // 0/1: i-parity within a stage
    const int blk  = blockIdx.x;
    const int i0   = blk * ICHUNK;

    float s[4][4];                           // [b-quad][m-quad]
    #pragma unroll
    for (int k = 0; k < 4; ++k)
        #pragma unroll
        for (int m = 0; m < 4; ++m) s[k][m] = 0.f;

    float v[4][4];
    if (MODE == 1) {
        #pragma unroll
        for (int k = 0; k < 4; ++k) {
            const float4 a = *(const float4*)
                &vsum[((bq + 16 * k) * JCAPS + j) * MDIM + mq * 4];
            v[k][0] = a.x; v[k][1] = a.y; v[k][2] = a.z; v[k][3] = a.w;
        }
    }

    for (int st = 0; st < NSTAGE; ++st) {
        // ---- stage W for IG i's into LDS (each thread: 8 contiguous floats) ----
        {
            const int iL  = tid >> 7;        // 0..7
            const int rem = tid & 127;       // 8-float chunk within the i
            const float4* src = (const float4*)(W + (size_t)(i0 + st * IG + iL) * 1024
                                                  + rem * 8);
            float4* dst = (float4*)&Wlds[iL * WI_STRIDE + (rem >> 4) * WJ_STRIDE
                                         + (rem & 15) * 8];
            dst[0] = src[0]; dst[1] = src[1];
        }
        __syncthreads();

        #pragma unroll
        for (int t = 0; t < IG / 2; ++t) {
            const int ii = t * 2 + isub;     // interleave parities
            const int i  = i0 + st * IG + ii;

            // x rows for the 4 b's (32 lanes share each address -> broadcast)
            float xs[4][8];
            #pragma unroll
            for (int k = 0; k < 4; ++k) {
                const size_t xo = ((size_t)(bq + 16 * k) * ICAPS + i) * NDIM;
                const float4 xa = *(const float4*)&x[xo];
                const float4 xb = *(const float4*)&x[xo + 4];
                xs[k][0] = xa.x; xs[k][1] = xa.y; xs[k][2] = xa.z; xs[k][3] = xa.w;
                xs[k][4] = xb.x; xs[k][5] = xb.y; xs[k][6] = xb.z; xs[k][7] = xb.w;
            }

            // u_hat m-quad for 4 b's: ONE b128 per n feeds 16 FMAs
            float u[4][4];
            #pragma unroll
            for (int k = 0; k < 4; ++k)
                #pragma unroll
                for (int m = 0; m < 4; ++m) u[k][m] = 0.f;
            const float* wb = &Wlds[ii * WI_STRIDE + j * WJ_STRIDE + mq * 4];
            #pragma unroll
            for (int n = 0; n < NDIM; ++n) {
                const float4 wq = *(const float4*)&wb[n * MDIM];
                #pragma unroll
                for (int k = 0; k < 4; ++k) {
                    const float xn = xs[k][n];
                    u[k][0] += xn * wq.x; u[k][1] += xn * wq.y;
                    u[k][2] += xn * wq.z; u[k][3] += xn * wq.w;
                }
            }

            if (MODE == 0) {
                #pragma unroll
                for (int k = 0; k < 4; ++k)
                    #pragma unroll
                    for (int m = 0; m < 4; ++m) s[k][m] += u[k][m];
            } else {
                // partial logit over this m-quad (4 independent chains)
                float lp[4];
                #pragma unroll
                for (int k = 0; k < 4; ++k)
                    lp[k] = u[k][0] * v[k][0] + u[k][1] * v[k][1]
                          + u[k][2] * v[k][2] + u[k][3] * v[k][3];
                // complete m-dot across the 4 mq lanes (bits 0,1: DPP quad-perm)
                #pragma unroll
                for (int k = 0; k < 4; ++k) lp[k] += __shfl_xor(lp[k], 1);
                #pragma unroll
                for (int k = 0; k < 4; ++k) lp[k] += __shfl_xor(lp[k], 2);
                // softmax over the 8 j-lanes (bits 2-4). |logit| small -> no max.
                float e[4], d[4];
                #pragma unroll
                for (int k = 0; k < 4; ++k) { e[k] = __expf(lp[k]); d[k] = e[k]; }
                #pragma unroll
                for (int k = 0; k < 4; ++k) d[k] += __shfl_xor(d[k], 4);
                #pragma unroll
                for (int k = 0; k < 4; ++k) d[k] += __shfl_xor(d[k], 8);
                #pragma unroll
                for (int k = 0; k < 4; ++k) d[k] += __shfl_xor(d[k], 16);
                #pragma unroll
                for (int k = 0; k < 4; ++k) {
                    const float c = e[k] * __builtin_amdgcn_rcpf(d[k]);
                    #pragma unroll
                    for (int m = 0; m < 4; ++m) s[k][m] += c * u[k][m];
                }
            }
        }
        __syncthreads();
    }

    // ---- combine i-parity halves via LDS (Wlds reuse is safe: synced) ----
    float* red = Wlds;                       // 8192 floats = 32 KB
    if (isub == 1) {
        #pragma unroll
        for (int k = 0; k < 4; ++k) {
            float4 o;
            o.x = s[k][0]; o.y = s[k][1]; o.z = s[k][2]; o.w = s[k][3];
            *(float4*)&red[((bq + 16 * k) * JCAPS + j) * MDIM + mq * 4] = o;
        }
    }
    __syncthreads();
    if (isub == 0) {
        const float sc = (MODE == 0) ? 0.125f : 1.0f;
        float* pp = partial + (size_t)blk * S_ELEMS;
        #pragma unroll
        for (int k = 0; k < 4; ++k) {
            const int off = ((bq + 16 * k) * JCAPS + j) * MDIM + mq * 4;
            const float4 r = *(const float4*)&red[off];
            float4 o;
            o.x = (s[k][0] + r.x) * sc; o.y = (s[k][1] + r.y) * sc;
            o.z = (s[k][2] + r.z) * sc; o.w = (s[k][3] + r.w) * sc;
            *(float4*)&pp[off] = o;
        }
    }
}

// Sum 256 partials -> s[b,j,m]; v = squash(s).
// OP 0: vsum = v (first pass, avoids memset)   OP 1: vsum += v   OP 2: out = v
template <int OP>
__global__ __launch_bounds__(256) void caps_reduce_kernel(
    const float* __restrict__ partial, float* __restrict__ vsum, float* __restrict__ out)
{
    __shared__ float sd[256];
    const int bo  = blockIdx.x;     // 0..127, each block covers 64 outputs
    const int tid = threadIdx.x;
    const int kg  = tid >> 6;       // 0..3  partial-group (64 partials each)
    const int tl  = tid & 63;       // output-within-block; lanes contiguous in t
    const int t   = bo * 64 + tl;   // global output index (= b*128 + j*16 + m)

    float a0 = 0.f, a1 = 0.f, a2 = 0.f, a3 = 0.f;
    const float* p = partial + (size_t)kg * 64 * S_ELEMS + t;
    #pragma unroll
    for (int k = 0; k < 64; k += 4) {
        a0 += p[(size_t)(k + 0) * S_ELEMS];
        a1 += p[(size_t)(k + 1) * S_ELEMS];
        a2 += p[(size_t)(k + 2) * S_ELEMS];
        a3 += p[(size_t)(k + 3) * S_ELEMS];
    }
    sd[tid] = (a0 + a1) + (a2 + a3);
    __syncthreads();

    if (tid < 64) {
        const float s = (sd[tid] + sd[64 + tid]) + (sd[128 + tid] + sd[192 + tid]);
        // squash: sn over the 16 m's of this (b,j) — lanes grouped by 16
        float sn = s * s;
        sn += __shfl_xor(sn, 1);
        sn += __shfl_xor(sn, 2);
        sn += __shfl_xor(sn, 4);
        sn += __shfl_xor(sn, 8);
        const float v = s * sqrtf(sn) / (1.f + sn);
        const int tt = bo * 64 + tid;
        if (OP == 2)      out[tt]   = v;
        else if (OP == 1) vsum[tt] += v;
        else              vsum[tt]  = v;
    }
}

extern "C" void kernel_launch(void* const* d_in, const int* in_sizes, int n_in,
                              void* d_out, int out_size, void* d_ws, size_t ws_size,
                              hipStream_t stream)
{
    const float* x = (const float*)d_in[0];   // [64, 8192, 8]
    const float* W = (const float*)d_in[1];   // [8192, 8, 8, 16]
    float* out = (float*)d_out;               // [64, 8, 16]

    float* partial = (float*)d_ws;                              // 256 * 8192 floats = 8 MB
    float* vsum    = partial + (size_t)NBLK * S_ELEMS;          // 8192 floats

    // pass 1: c uniform
    caps_pass_kernel<0><<<NBLK, 1024, 0, stream>>>(x, W, vsum, partial);
    caps_reduce_kernel<0><<<128, 256, 0, stream>>>(partial, vsum, nullptr);  // vsum = v1
    // pass 2: logits = dot(v1, u_hat)
    caps_pass_kernel<1><<<NBLK, 1024, 0, stream>>>(x, W, vsum, partial);
    caps_reduce_kernel<1><<<128, 256, 0, stream>>>(partial, vsum, nullptr);  // vsum = v1+v2
    // pass 3 (final): logits = dot(v1+v2, u_hat), output squash
    caps_pass_kernel<1><<<NBLK, 1024, 0, stream>>>(x, W, vsum, partial);
    caps_reduce_kernel<2><<<128, 256, 0, stream>>>(partial, vsum, out);
}

// Round 4
// 299.435 us; speedup vs baseline: 1.0267x; 1.0267x over previous
//
#include <hip/hip_runtime.h>

// ---------------------------------------------------------------------------
// CapsNet dynamic routing, fully fused, fp32.
//   x: [B=64, I=8192, N=8]   W: [I=8192, J=8, N=8, M=16]   out: [B, J=8, M=16]
//
// b_logits after t iters = dot(sum_{t'<=t} v_{t'}, u_hat); carry only
// vsum[B,J,M] between passes, recompute u_hat per pass (x,W are L3-resident).
//
// Pass kernel: 256 blocks x 1024 threads. Thread = (bq, j, mq, i-parity):
// owns b in {bq, bq+16, bq+32, bq+48} -> one ds_read_b128 of W feeds
// 4 b x 4 m x 8 n = 128 FMAs (W-LDS traffic 537 MB/pass, ~7 us/CU floor).
//
// SPILL FIX (round-3 lesson): the register allocator targets the occupancy
// implied by LDS size. At 33.8 KB it assumed 2 blocks/CU = 8 waves/EU and
// capped VGPRs at 64, spilling ~116 MB/pass to scratch (WRITE_SIZE 124 MB,
// pass 89 us). Padding static LDS to 84 KB (> 80 KB) makes the implied
// occupancy 1 block/CU = 4 waves/EU -> 128-VGPR budget -> no spill. Runtime
// occupancy is unchanged: grid 256 = 1 block/CU anyway.
//
// WJ_STRIDE=136 (8-bank j spacing): read addrs 8(j%4)+4mq mod 32 -> max
// 2-way start collision (free); the 132 stride was 4-way (4.46M cycles).
// Softmax: m-dot completed via DPP quad_perm xor1/xor2 (VALU pipe, not DS),
// j-denominator via shfl_xor 4/8/16 (ds_swizzle). No max-subtract (|logit|<~1).
// Reduce kernel: coalesced 256-partial sum + squash; first call writes vsum.
// ---------------------------------------------------------------------------

#define BB      64
#define ICAPS   8192
#define NDIM    8
#define JCAPS   8
#define MDIM    16
#define NBLK    256
#define ICHUNK  (ICAPS / NBLK)        // 32
#define IG      8                     // i's staged per barrier
#define NSTAGE  (ICHUNK / IG)         // 4
#define WJ_STRIDE 136                 // 136 mod 32 = 8 -> j-rows 8 banks apart
#define WI_STRIDE (JCAPS * WJ_STRIDE) // 1088 floats per i
#define S_ELEMS  (BB * JCAPS * MDIM)  // 8192 floats per s / vsum / out

// butterfly add over lanes differing in quad bits: xor1 = quad_perm(1,0,3,2),
// xor2 = quad_perm(2,3,0,1). Pure VALU (DPP), keeps the DS pipe free.
template <int CTRL>
__device__ __forceinline__ float dpp_xadd(float v) {
    const int p = __builtin_amdgcn_mov_dpp(__float_as_int(v), CTRL, 0xF, 0xF, true);
    return v + __int_as_float(p);
}
#define DPP_XOR1 0xB1   // quad_perm [1,0,3,2]
#define DPP_XOR2 0x4E   // quad_perm [2,3,0,1]

// MODE 0: uniform c = 1/8 (softmax of zero logits)
// MODE 1: c = softmax_j( dot(vsum[b,j,:], u_hat[b,i,j,:]) )
template <int MODE>
__global__ __launch_bounds__(1024, 4)
void caps_pass_kernel(
    const float* __restrict__ x, const float* __restrict__ W,
    const float* __restrict__ vsum, float* __restrict__ partial)
{
    __shared__ float Wlds[IG * WI_STRIDE];   // 34,816 B; reused for final reduce
    __shared__ float occ_pad[12288];         // 49,152 B -> 83,968 B total (>80K):
                                             // forces RA to assume 1 blk/CU
    // never-true at runtime (grid=256); opaque to the compiler so occ_pad stays
    if (blockIdx.x >= 0x40000000u) ((volatile float*)occ_pad)[threadIdx.x & 1023] = 1.f;

    const int tid  = threadIdx.x;            // 0..1023
    const int mq   = tid & 3;                // m-quad (lane bits 0-1)
    const int j    = (tid >> 2) & 7;         // out-cap (lane bits 2-4)
    const int bq   = (tid >> 5) & 15;        // batch-quad base
    const int isub = tid >> 9;               // 0/1: i-parity within a stage
    const int blk  = blockIdx.x;
    const int i0   = blk * ICHUNK;

    float s[4][4];                           // [b-quad][m-quad]
    #pragma unroll
    for (int k = 0; k < 4; ++k)
        #pragma unroll
        for (int m = 0; m < 4; ++m) s[k][m] = 0.f;

    float v[4][4];
    if (MODE == 1) {
        #pragma unroll
        for (int k = 0; k < 4; ++k) {
            const float4 a = *(const float4*)
                &vsum[((bq + 16 * k) * JCAPS + j) * MDIM + mq * 4];
            v[k][0] = a.x; v[k][1] = a.y; v[k][2] = a.z; v[k][3] = a.w;
        }
    }

    for (int st = 0; st < NSTAGE; ++st) {
        // ---- stage W for IG i's into LDS (each thread: 8 contiguous floats) ----
        {
            const int iL  = tid >> 7;        // 0..7
            const int rem = tid & 127;       // 8-float chunk within the i
            const float4* src = (const float4*)(W + (size_t)(i0 + st * IG + iL) * 1024
                                                  + rem * 8);
            float4* dst = (float4*)&Wlds[iL * WI_STRIDE + (rem >> 4) * WJ_STRIDE
                                         + (rem & 15) * 8];
            dst[0] = src[0]; dst[1] = src[1];
        }
        __syncthreads();

        #pragma unroll
        for (int t = 0; t < IG / 2; ++t) {
            const int ii = t * 2 + isub;     // interleave parities
            const int i  = i0 + st * IG + ii;

            float u[4][4];
            #pragma unroll
            for (int k = 0; k < 4; ++k)
                #pragma unroll
                for (int m = 0; m < 4; ++m) u[k][m] = 0.f;
            const float* wb = &Wlds[ii * WI_STRIDE + j * WJ_STRIDE + mq * 4];

            // n-split: keep only 16 x-floats live at a time (VGPR pressure)
            {   // n = 0..3
                float4 xa[4];
                #pragma unroll
                for (int k = 0; k < 4; ++k)
                    xa[k] = *(const float4*)&x[((size_t)(bq + 16 * k) * ICAPS + i) * NDIM];
                #pragma unroll
                for (int n = 0; n < 4; ++n) {
                    const float4 wq = *(const float4*)&wb[n * MDIM];
                    #pragma unroll
                    for (int k = 0; k < 4; ++k) {
                        const float xn = (n == 0) ? xa[k].x : (n == 1) ? xa[k].y
                                       : (n == 2) ? xa[k].z : xa[k].w;
                        u[k][0] += xn * wq.x; u[k][1] += xn * wq.y;
                        u[k][2] += xn * wq.z; u[k][3] += xn * wq.w;
                    }
                }
            }
            {   // n = 4..7
                float4 xb[4];
                #pragma unroll
                for (int k = 0; k < 4; ++k)
                    xb[k] = *(const float4*)&x[((size_t)(bq + 16 * k) * ICAPS + i) * NDIM + 4];
                #pragma unroll
                for (int n = 0; n < 4; ++n) {
                    const float4 wq = *(const float4*)&wb[(n + 4) * MDIM];
                    #pragma unroll
                    for (int k = 0; k < 4; ++k) {
                        const float xn = (n == 0) ? xb[k].x : (n == 1) ? xb[k].y
                                       : (n == 2) ? xb[k].z : xb[k].w;
                        u[k][0] += xn * wq.x; u[k][1] += xn * wq.y;
                        u[k][2] += xn * wq.z; u[k][3] += xn * wq.w;
                    }
                }
            }

            if (MODE == 0) {
                #pragma unroll
                for (int k = 0; k < 4; ++k)
                    #pragma unroll
                    for (int m = 0; m < 4; ++m) s[k][m] += u[k][m];
            } else {
                // partial logit over this m-quad (4 independent chains)
                float lp[4];
                #pragma unroll
                for (int k = 0; k < 4; ++k)
                    lp[k] = u[k][0] * v[k][0] + u[k][1] * v[k][1]
                          + u[k][2] * v[k][2] + u[k][3] * v[k][3];
                // complete m-dot across the 4 mq lanes: DPP quad_perm (VALU)
                #pragma unroll
                for (int k = 0; k < 4; ++k) lp[k] = dpp_xadd<DPP_XOR1>(lp[k]);
                #pragma unroll
                for (int k = 0; k < 4; ++k) lp[k] = dpp_xadd<DPP_XOR2>(lp[k]);
                // softmax over the 8 j-lanes (bits 2-4). |logit| small -> no max.
                float e[4], d[4];
                #pragma unroll
                for (int k = 0; k < 4; ++k) { e[k] = __expf(lp[k]); d[k] = e[k]; }
                #pragma unroll
                for (int k = 0; k < 4; ++k) d[k] += __shfl_xor(d[k], 4);
                #pragma unroll
                for (int k = 0; k < 4; ++k) d[k] += __shfl_xor(d[k], 8);
                #pragma unroll
                for (int k = 0; k < 4; ++k) d[k] += __shfl_xor(d[k], 16);
                #pragma unroll
                for (int k = 0; k < 4; ++k) {
                    const float c = e[k] * __builtin_amdgcn_rcpf(d[k]);
                    #pragma unroll
                    for (int m = 0; m < 4; ++m) s[k][m] += c * u[k][m];
                }
            }
        }
        __syncthreads();
    }

    // ---- combine i-parity halves via LDS (Wlds reuse is safe: synced) ----
    float* red = Wlds;                       // 8192 floats needed, 8704 available
    if (isub == 1) {
        #pragma unroll
        for (int k = 0; k < 4; ++k) {
            float4 o;
            o.x = s[k][0]; o.y = s[k][1]; o.z = s[k][2]; o.w = s[k][3];
            *(float4*)&red[((bq + 16 * k) * JCAPS + j) * MDIM + mq * 4] = o;
        }
    }
    __syncthreads();
    if (isub == 0) {
        const float sc = (MODE == 0) ? 0.125f : 1.0f;
        float* pp = partial + (size_t)blk * S_ELEMS;
        #pragma unroll
        for (int k = 0; k < 4; ++k) {
            const int off = ((bq + 16 * k) * JCAPS + j) * MDIM + mq * 4;
            const float4 r = *(const float4*)&red[off];
            float4 o;
            o.x = (s[k][0] + r.x) * sc; o.y = (s[k][1] + r.y) * sc;
            o.z = (s[k][2] + r.z) * sc; o.w = (s[k][3] + r.w) * sc;
            *(float4*)&pp[off] = o;
        }
    }
}

// Sum 256 partials -> s[b,j,m]; v = squash(s).
// OP 0: vsum = v (first pass, avoids memset)   OP 1: vsum += v   OP 2: out = v
template <int OP>
__global__ __launch_bounds__(256) void caps_reduce_kernel(
    const float* __restrict__ partial, float* __restrict__ vsum, float* __restrict__ out)
{
    __shared__ float sd[256];
    const int bo  = blockIdx.x;     // 0..127, each block covers 64 outputs
    const int tid = threadIdx.x;
    const int kg  = tid >> 6;       // 0..3  partial-group (64 partials each)
    const int tl  = tid & 63;       // output-within-block; lanes contiguous in t
    const int t   = bo * 64 + tl;   // global output index (= b*128 + j*16 + m)

    float a0 = 0.f, a1 = 0.f, a2 = 0.f, a3 = 0.f;
    const float* p = partial + (size_t)kg * 64 * S_ELEMS + t;
    #pragma unroll
    for (int k = 0; k < 64; k += 4) {
        a0 += p[(size_t)(k + 0) * S_ELEMS];
        a1 += p[(size_t)(k + 1) * S_ELEMS];
        a2 += p[(size_t)(k + 2) * S_ELEMS];
        a3 += p[(size_t)(k + 3) * S_ELEMS];
    }
    sd[tid] = (a0 + a1) + (a2 + a3);
    __syncthreads();

    if (tid < 64) {
        const float s = (sd[tid] + sd[64 + tid]) + (sd[128 + tid] + sd[192 + tid]);
        // squash: sn over the 16 m's of this (b,j) — lanes grouped by 16
        float sn = s * s;
        sn += __shfl_xor(sn, 1);
        sn += __shfl_xor(sn, 2);
        sn += __shfl_xor(sn, 4);
        sn += __shfl_xor(sn, 8);
        const float v = s * sqrtf(sn) / (1.f + sn);
        const int tt = bo * 64 + tid;
        if (OP == 2)      out[tt]   = v;
        else if (OP == 1) vsum[tt] += v;
        else              vsum[tt]  = v;
    }
}

extern "C" void kernel_launch(void* const* d_in, const int* in_sizes, int n_in,
                              void* d_out, int out_size, void* d_ws, size_t ws_size,
                              hipStream_t stream)
{
    const float* x = (const float*)d_in[0];   // [64, 8192, 8]
    const float* W = (const float*)d_in[1];   // [8192, 8, 8, 16]
    float* out = (float*)d_out;               // [64, 8, 16]

    float* partial = (float*)d_ws;                              // 256 * 8192 floats = 8 MB
    float* vsum    = partial + (size_t)NBLK * S_ELEMS;          // 8192 floats

    // pass 1: c uniform
    caps_pass_kernel<0><<<NBLK, 1024, 0, stream>>>(x, W, vsum, partial);
    caps_reduce_kernel<0><<<128, 256, 0, stream>>>(partial, vsum, nullptr);  // vsum = v1
    // pass 2: logits = dot(v1, u_hat)
    caps_pass_kernel<1><<<NBLK, 1024, 0, stream>>>(x, W, vsum, partial);
    caps_reduce_kernel<1><<<128, 256, 0, stream>>>(partial, vsum, nullptr);  // vsum = v1+v2
    // pass 3 (final): logits = dot(v1+v2, u_hat), output squash
    caps_pass_kernel<1><<<NBLK, 1024, 0, stream>>>(x, W, vsum, partial);
    caps_reduce_kernel<2><<<128, 256, 0, stream>>>(partial, vsum, out);
}

// Round 5
// 263.296 us; speedup vs baseline: 1.1676x; 1.1373x over previous
//
#include <hip/hip_runtime.h>

// ---------------------------------------------------------------------------
// CapsNet dynamic routing, fully fused, fp32.
//   x: [B=64, I=8192, N=8]   W: [I=8192, J=8, N=8, M=16]   out: [B, J=8, M=16]
//
// b_logits after t iters = dot(sum_{t'<=t} v_{t'}, u_hat); carry only
// vsum[B,J,M] between passes, recompute u_hat per pass (x,W are L3-resident).
//
// Pass kernel: 256 blocks x 1024 threads. Thread = (bq, j, mq, i-parity):
// owns b in {bq, bq+16, bq+32, bq+48} -> one ds_read_b128 of W feeds
// 4 b x 4 m x 8 n = 128 FMAs (W-LDS traffic 537 MB/pass, ~10 us/CU floor).
//
// SPILL FIX (rounds 3-4 lesson): __launch_bounds__ second arg is MIN waves
// per EU — a floor, not a cap. With (1024,4) or bare (1024) the compiler
// targets 8 waves/EU and caps VGPRs at 64, spilling ~100 MB/pass to scratch
// (WRITE_SIZE 101-124 MB, pass 79-107 us). Round 0's (512,1) measured
// VGPR=100 with zero spill. (1024,1) releases the floor; launchability of a
// 16-wave block still caps allocation at 128 VGPRs — enough for the ~85-float
// live state of the G=4 layout. LDS-padding / amdgpu_waves_per_eu do NOT
// move the budget (measured rounds 3-4) — do not reintroduce them.
//
// WJ_STRIDE=136 (8-bank j spacing): read starts 8(j%4)+4mq mod 32 -> exact
// 2-way per phase (free per m136).
// Softmax: m-dot completed via DPP quad_perm xor1/xor2 (VALU pipe, not DS),
// j-denominator via shfl_xor 4/8/16 (ds_swizzle). No max-subtract (|logit|<~1).
// Reduce kernel: coalesced 256-partial sum + squash; first call writes vsum.
// ---------------------------------------------------------------------------

#define BB      64
#define ICAPS   8192
#define NDIM    8
#define JCAPS   8
#define MDIM    16
#define NBLK    256
#define ICHUNK  (ICAPS / NBLK)        // 32
#define IG      8                     // i's staged per barrier
#define NSTAGE  (ICHUNK / IG)         // 4
#define WJ_STRIDE 136                 // 136 mod 32 = 8 -> j-rows 8 banks apart
#define WI_STRIDE (JCAPS * WJ_STRIDE) // 1088 floats per i
#define S_ELEMS  (BB * JCAPS * MDIM)  // 8192 floats per s / vsum / out

// butterfly add over lanes differing in quad bits: xor1 = quad_perm(1,0,3,2),
// xor2 = quad_perm(2,3,0,1). Pure VALU (DPP), keeps the DS pipe free.
template <int CTRL>
__device__ __forceinline__ float dpp_xadd(float v) {
    const int p = __builtin_amdgcn_mov_dpp(__float_as_int(v), CTRL, 0xF, 0xF, true);
    return v + __int_as_float(p);
}
#define DPP_XOR1 0xB1   // quad_perm [1,0,3,2]
#define DPP_XOR2 0x4E   // quad_perm [2,3,0,1]

// MODE 0: uniform c = 1/8 (softmax of zero logits)
// MODE 1: c = softmax_j( dot(vsum[b,j,:], u_hat[b,i,j,:]) )
template <int MODE>
__global__ __launch_bounds__(1024, 1)
void caps_pass_kernel(
    const float* __restrict__ x, const float* __restrict__ W,
    const float* __restrict__ vsum, float* __restrict__ partial)
{
    __shared__ float Wlds[IG * WI_STRIDE];   // 34,816 B; reused for final reduce

    const int tid  = threadIdx.x;            // 0..1023
    const int mq   = tid & 3;                // m-quad (lane bits 0-1)
    const int j    = (tid >> 2) & 7;         // out-cap (lane bits 2-4)
    const int bq   = (tid >> 5) & 15;        // batch-quad base
    const int isub = tid >> 9;               // 0/1: i-parity within a stage
    const int blk  = blockIdx.x;
    const int i0   = blk * ICHUNK;

    float s[4][4];                           // [b-quad][m-quad]
    #pragma unroll
    for (int k = 0; k < 4; ++k)
        #pragma unroll
        for (int m = 0; m < 4; ++m) s[k][m] = 0.f;

    float v[4][4];
    if (MODE == 1) {
        #pragma unroll
        for (int k = 0; k < 4; ++k) {
            const float4 a = *(const float4*)
                &vsum[((bq + 16 * k) * JCAPS + j) * MDIM + mq * 4];
            v[k][0] = a.x; v[k][1] = a.y; v[k][2] = a.z; v[k][3] = a.w;
        }
    }

    for (int st = 0; st < NSTAGE; ++st) {
        // ---- stage W for IG i's into LDS (each thread: 8 contiguous floats) ----
        {
            const int iL  = tid >> 7;        // 0..7
            const int rem = tid & 127;       // 8-float chunk within the i
            const float4* src = (const float4*)(W + (size_t)(i0 + st * IG + iL) * 1024
                                                  + rem * 8);
            float4* dst = (float4*)&Wlds[iL * WI_STRIDE + (rem >> 4) * WJ_STRIDE
                                         + (rem & 15) * 8];
            dst[0] = src[0]; dst[1] = src[1];
        }
        __syncthreads();

        #pragma unroll
        for (int t = 0; t < IG / 2; ++t) {
            const int ii = t * 2 + isub;     // interleave parities
            const int i  = i0 + st * IG + ii;

            float u[4][4];
            #pragma unroll
            for (int k = 0; k < 4; ++k)
                #pragma unroll
                for (int m = 0; m < 4; ++m) u[k][m] = 0.f;
            const float* wb = &Wlds[ii * WI_STRIDE + j * WJ_STRIDE + mq * 4];

            // n-split: keep only 16 x-floats live at a time (VGPR pressure)
            {   // n = 0..3
                float4 xa[4];
                #pragma unroll
                for (int k = 0; k < 4; ++k)
                    xa[k] = *(const float4*)&x[((size_t)(bq + 16 * k) * ICAPS + i) * NDIM];
                #pragma unroll
                for (int n = 0; n < 4; ++n) {
                    const float4 wq = *(const float4*)&wb[n * MDIM];
                    #pragma unroll
                    for (int k = 0; k < 4; ++k) {
                        const float xn = (n == 0) ? xa[k].x : (n == 1) ? xa[k].y
                                       : (n == 2) ? xa[k].z : xa[k].w;
                        u[k][0] += xn * wq.x; u[k][1] += xn * wq.y;
                        u[k][2] += xn * wq.z; u[k][3] += xn * wq.w;
                    }
                }
            }
            {   // n = 4..7
                float4 xb[4];
                #pragma unroll
                for (int k = 0; k < 4; ++k)
                    xb[k] = *(const float4*)&x[((size_t)(bq + 16 * k) * ICAPS + i) * NDIM + 4];
                #pragma unroll
                for (int n = 0; n < 4; ++n) {
                    const float4 wq = *(const float4*)&wb[(n + 4) * MDIM];
                    #pragma unroll
                    for (int k = 0; k < 4; ++k) {
                        const float xn = (n == 0) ? xb[k].x : (n == 1) ? xb[k].y
                                       : (n == 2) ? xb[k].z : xb[k].w;
                        u[k][0] += xn * wq.x; u[k][1] += xn * wq.y;
                        u[k][2] += xn * wq.z; u[k][3] += xn * wq.w;
                    }
                }
            }

            if (MODE == 0) {
                #pragma unroll
                for (int k = 0; k < 4; ++k)
                    #pragma unroll
                    for (int m = 0; m < 4; ++m) s[k][m] += u[k][m];
            } else {
                // partial logit over this m-quad (4 independent chains)
                float lp[4];
                #pragma unroll
                for (int k = 0; k < 4; ++k)
                    lp[k] = u[k][0] * v[k][0] + u[k][1] * v[k][1]
                          + u[k][2] * v[k][2] + u[k][3] * v[k][3];
                // complete m-dot across the 4 mq lanes: DPP quad_perm (VALU)
                #pragma unroll
                for (int k = 0; k < 4; ++k) lp[k] = dpp_xadd<DPP_XOR1>(lp[k]);
                #pragma unroll
                for (int k = 0; k < 4; ++k) lp[k] = dpp_xadd<DPP_XOR2>(lp[k]);
                // softmax over the 8 j-lanes (bits 2-4). |logit| small -> no max.
                float e[4], d[4];
                #pragma unroll
                for (int k = 0; k < 4; ++k) { e[k] = __expf(lp[k]); d[k] = e[k]; }
                #pragma unroll
                for (int k = 0; k < 4; ++k) d[k] += __shfl_xor(d[k], 4);
                #pragma unroll
                for (int k = 0; k < 4; ++k) d[k] += __shfl_xor(d[k], 8);
                #pragma unroll
                for (int k = 0; k < 4; ++k) d[k] += __shfl_xor(d[k], 16);
                #pragma unroll
                for (int k = 0; k < 4; ++k) {
                    const float c = e[k] * __builtin_amdgcn_rcpf(d[k]);
                    #pragma unroll
                    for (int m = 0; m < 4; ++m) s[k][m] += c * u[k][m];
                }
            }
        }
        __syncthreads();
    }

    // ---- combine i-parity halves via LDS (Wlds reuse is safe: synced) ----
    float* red = Wlds;                       // 8192 floats needed, 8704 available
    if (isub == 1) {
        #pragma unroll
        for (int k = 0; k < 4; ++k) {
            float4 o;
            o.x = s[k][0]; o.y = s[k][1]; o.z = s[k][2]; o.w = s[k][3];
            *(float4*)&red[((bq + 16 * k) * JCAPS + j) * MDIM + mq * 4] = o;
        }
    }
    __syncthreads();
    if (isub == 0) {
        const float sc = (MODE == 0) ? 0.125f : 1.0f;
        float* pp = partial + (size_t)blk * S_ELEMS;
        #pragma unroll
        for (int k = 0; k < 4; ++k) {
            const int off = ((bq + 16 * k) * JCAPS + j) * MDIM + mq * 4;
            const float4 r = *(const float4*)&red[off];
            float4 o;
            o.x = (s[k][0] + r.x) * sc; o.y = (s[k][1] + r.y) * sc;
            o.z = (s[k][2] + r.z) * sc; o.w = (s[k][3] + r.w) * sc;
            *(float4*)&pp[off] = o;
        }
    }
}

// Sum 256 partials -> s[b,j,m]; v = squash(s).
// OP 0: vsum = v (first pass, avoids memset)   OP 1: vsum += v   OP 2: out = v
template <int OP>
__global__ __launch_bounds__(256) void caps_reduce_kernel(
    const float* __restrict__ partial, float* __restrict__ vsum, float* __restrict__ out)
{
    __shared__ float sd[256];
    const int bo  = blockIdx.x;     // 0..127, each block covers 64 outputs
    const int tid = threadIdx.x;
    const int kg  = tid >> 6;       // 0..3  partial-group (64 partials each)
    const int tl  = tid & 63;       // output-within-block; lanes contiguous in t
    const int t   = bo * 64 + tl;   // global output index (= b*128 + j*16 + m)

    float a0 = 0.f, a1 = 0.f, a2 = 0.f, a3 = 0.f;
    const float* p = partial + (size_t)kg * 64 * S_ELEMS + t;
    #pragma unroll
    for (int k = 0; k < 64; k += 4) {
        a0 += p[(size_t)(k + 0) * S_ELEMS];
        a1 += p[(size_t)(k + 1) * S_ELEMS];
        a2 += p[(size_t)(k + 2) * S_ELEMS];
        a3 += p[(size_t)(k + 3) * S_ELEMS];
    }
    sd[tid] = (a0 + a1) + (a2 + a3);
    __syncthreads();

    if (tid < 64) {
        const float s = (sd[tid] + sd[64 + tid]) + (sd[128 + tid] + sd[192 + tid]);
        // squash: sn over the 16 m's of this (b,j) — lanes grouped by 16
        float sn = s * s;
        sn += __shfl_xor(sn, 1);
        sn += __shfl_xor(sn, 2);
        sn += __shfl_xor(sn, 4);
        sn += __shfl_xor(sn, 8);
        const float v = s * sqrtf(sn) / (1.f + sn);
        const int tt = bo * 64 + tid;
        if (OP == 2)      out[tt]   = v;
        else if (OP == 1) vsum[tt] += v;
        else              vsum[tt]  = v;
    }
}

extern "C" void kernel_launch(void* const* d_in, const int* in_sizes, int n_in,
                              void* d_out, int out_size, void* d_ws, size_t ws_size,
                              hipStream_t stream)
{
    const float* x = (const float*)d_in[0];   // [64, 8192, 8]
    const float* W = (const float*)d_in[1];   // [8192, 8, 8, 16]
    float* out = (float*)d_out;               // [64, 8, 16]

    float* partial = (float*)d_ws;                              // 256 * 8192 floats = 8 MB
    float* vsum    = partial + (size_t)NBLK * S_ELEMS;          // 8192 floats

    // pass 1: c uniform
    caps_pass_kernel<0><<<NBLK, 1024, 0, stream>>>(x, W, vsum, partial);
    caps_reduce_kernel<0><<<128, 256, 0, stream>>>(partial, vsum, nullptr);  // vsum = v1
    // pass 2: logits = dot(v1, u_hat)
    caps_pass_kernel<1><<<NBLK, 1024, 0, stream>>>(x, W, vsum, partial);
    caps_reduce_kernel<1><<<128, 256, 0, stream>>>(partial, vsum, nullptr);  // vsum = v1+v2
    // pass 3 (final): logits = dot(v1+v2, u_hat), output squash
    caps_pass_kernel<1><<<NBLK, 1024, 0, stream>>>(x, W, vsum, partial);
    caps_reduce_kernel<2><<<128, 256, 0, stream>>>(partial, vsum, out);
}

// Round 6
// 184.884 us; speedup vs baseline: 1.6628x; 1.4241x over previous
//
#include <hip/hip_runtime.h>

// ---------------------------------------------------------------------------
// CapsNet dynamic routing, fully fused, fp32.
//   x: [B=64, I=8192, N=8]   W: [I=8192, J=8, N=8, M=16]   out: [B, J=8, M=16]
//
// b_logits after t iters = dot(sum_{t'<=t} v_{t'}, u_hat); carry only
// vsum[B,J,M] between passes, recompute u_hat per pass (x,W are L3-resident).
//
// BLOCK SHAPE (rounds 3-5 lesson): 1024-thread blocks are hard-capped at 64
// VGPRs by this toolchain — amdgpu_waves_per_eu(4,4), 84KB LDS padding, and
// __launch_bounds__(1024,1) ALL failed to raise it, each spilling ~100 MB/pass
// (WRITE_SIZE 95-124 MB, pass 70-107 us). 512-thread blocks with
// __launch_bounds__(512,1) measurably get VGPR=100 with zero spill (round 0).
// So: 256 blocks x 512 threads, thread = (bq, j, mq), no i-parity split.
//
// Thread owns b in {bq, bq+16, bq+32, bq+48}: one ds_read_b128 of W feeds
// 4 b x 4 m = 16 FMAs -> W-LDS traffic 537 MB/pass (~10 us/CU DS floor).
// Live state ~90 floats fits the 512-shape register budget.
//
// WJ_STRIDE=136 (8-bank j spacing): b128 spans [8j+4mq, +3] mod 32 -> exact
// 2-way overlap per 32-lane phase (free per m136).
// Softmax cross-lane work stays off the DS pipe where possible:
//   m-dot reduce:   DPP quad_perm xor1/xor2 (VALU).
//   j-denominator:  DPP row_ror:4 + row_ror:8 (valid: after the quad reduce
//     each quad is uniform, so lanes {l,l+4,l+8,l+12} hold the 4 distinct j's
//     of the 16-row) + ONE shfl_xor(16) for the cross-row half.
// No max-subtract (|logit| <~ 1).
// Reduce kernel: coalesced 256-partial sum + squash; first call writes vsum
// (no memset dispatch).
// ---------------------------------------------------------------------------

#define BB      64
#define ICAPS   8192
#define NDIM    8
#define JCAPS   8
#define MDIM    16
#define NBLK    256
#define ICHUNK  (ICAPS / NBLK)        // 32
#define IG      8                     // i's staged per barrier
#define NSTAGE  (ICHUNK / IG)         // 4
#define WJ_STRIDE 136                 // 136 mod 32 = 8 -> j-rows 8 banks apart
#define WI_STRIDE (JCAPS * WJ_STRIDE) // 1088 floats per i
#define S_ELEMS  (BB * JCAPS * MDIM)  // 8192 floats per s / vsum / out

// butterfly / rotate adds on the VALU pipe via DPP.
template <int CTRL>
__device__ __forceinline__ float dpp_xadd(float v) {
    const int p = __builtin_amdgcn_mov_dpp(__float_as_int(v), CTRL, 0xF, 0xF, true);
    return v + __int_as_float(p);
}
#define DPP_XOR1 0xB1   // quad_perm [1,0,3,2]
#define DPP_XOR2 0x4E   // quad_perm [2,3,0,1]
#define DPP_ROR4 0x124  // row_ror:4
#define DPP_ROR8 0x128  // row_ror:8

// MODE 0: uniform c = 1/8 (softmax of zero logits)
// MODE 1: c = softmax_j( dot(vsum[b,j,:], u_hat[b,i,j,:]) )
template <int MODE>
__global__ __launch_bounds__(512, 1)
void caps_pass_kernel(
    const float* __restrict__ x, const float* __restrict__ W,
    const float* __restrict__ vsum, float* __restrict__ partial)
{
    __shared__ float Wlds[IG * WI_STRIDE];   // 34,816 B

    const int tid = threadIdx.x;             // 0..511
    const int mq  = tid & 3;                 // m-quad (lane bits 0-1)
    const int j   = (tid >> 2) & 7;          // out-cap (lane bits 2-4)
    const int bq  = tid >> 5;                // 0..15 batch-quad base
    const int blk = blockIdx.x;
    const int i0  = blk * ICHUNK;

    float s[4][4];                           // [b-quad][m-quad]
    #pragma unroll
    for (int k = 0; k < 4; ++k)
        #pragma unroll
        for (int m = 0; m < 4; ++m) s[k][m] = 0.f;

    float v[4][4];
    if (MODE == 1) {
        #pragma unroll
        for (int k = 0; k < 4; ++k) {
            const float4 a = *(const float4*)
                &vsum[((bq + 16 * k) * JCAPS + j) * MDIM + mq * 4];
            v[k][0] = a.x; v[k][1] = a.y; v[k][2] = a.z; v[k][3] = a.w;
        }
    }

    for (int st = 0; st < NSTAGE; ++st) {
        // ---- stage W for IG i's into LDS (each thread: 16 contiguous floats) ----
        {
            const int iL  = tid >> 6;        // 0..7
            const int rem = tid & 63;        // 16-float chunk within the i
            const float4* src = (const float4*)(W + (size_t)(i0 + st * IG + iL) * 1024
                                                  + rem * 16);
            float4* dst = (float4*)&Wlds[iL * WI_STRIDE + (rem >> 3) * WJ_STRIDE
                                         + (rem & 7) * 16];
            dst[0] = src[0]; dst[1] = src[1]; dst[2] = src[2]; dst[3] = src[3];
        }
        __syncthreads();

        #pragma unroll
        for (int ii = 0; ii < IG; ++ii) {
            const int i = i0 + st * IG + ii;

            float u[4][4];
            #pragma unroll
            for (int k = 0; k < 4; ++k)
                #pragma unroll
                for (int m = 0; m < 4; ++m) u[k][m] = 0.f;
            const float* wb = &Wlds[ii * WI_STRIDE + j * WJ_STRIDE + mq * 4];

            // n-split: keep only 16 x-floats live at a time (VGPR pressure)
            {   // n = 0..3
                float4 xa[4];
                #pragma unroll
                for (int k = 0; k < 4; ++k)
                    xa[k] = *(const float4*)&x[((size_t)(bq + 16 * k) * ICAPS + i) * NDIM];
                #pragma unroll
                for (int n = 0; n < 4; ++n) {
                    const float4 wq = *(const float4*)&wb[n * MDIM];
                    #pragma unroll
                    for (int k = 0; k < 4; ++k) {
                        const float xn = (n == 0) ? xa[k].x : (n == 1) ? xa[k].y
                                       : (n == 2) ? xa[k].z : xa[k].w;
                        u[k][0] += xn * wq.x; u[k][1] += xn * wq.y;
                        u[k][2] += xn * wq.z; u[k][3] += xn * wq.w;
                    }
                }
            }
            {   // n = 4..7
                float4 xb[4];
                #pragma unroll
                for (int k = 0; k < 4; ++k)
                    xb[k] = *(const float4*)&x[((size_t)(bq + 16 * k) * ICAPS + i) * NDIM + 4];
                #pragma unroll
                for (int n = 0; n < 4; ++n) {
                    const float4 wq = *(const float4*)&wb[(n + 4) * MDIM];
                    #pragma unroll
                    for (int k = 0; k < 4; ++k) {
                        const float xn = (n == 0) ? xb[k].x : (n == 1) ? xb[k].y
                                       : (n == 2) ? xb[k].z : xb[k].w;
                        u[k][0] += xn * wq.x; u[k][1] += xn * wq.y;
                        u[k][2] += xn * wq.z; u[k][3] += xn * wq.w;
                    }
                }
            }

            if (MODE == 0) {
                #pragma unroll
                for (int k = 0; k < 4; ++k)
                    #pragma unroll
                    for (int m = 0; m < 4; ++m) s[k][m] += u[k][m];
            } else {
                // partial logit over this m-quad (4 independent chains)
                float lp[4];
                #pragma unroll
                for (int k = 0; k < 4; ++k)
                    lp[k] = u[k][0] * v[k][0] + u[k][1] * v[k][1]
                          + u[k][2] * v[k][2] + u[k][3] * v[k][3];
                // complete m-dot across the 4 mq lanes: DPP quad_perm (VALU)
                #pragma unroll
                for (int k = 0; k < 4; ++k) lp[k] = dpp_xadd<DPP_XOR1>(lp[k]);
                #pragma unroll
                for (int k = 0; k < 4; ++k) lp[k] = dpp_xadd<DPP_XOR2>(lp[k]);
                // softmax over 8 j's. Quads now uniform -> row_ror:4/8 sums the
                // 4 distinct j's of this 16-row on the VALU pipe; one
                // shfl_xor(16) folds in the other row. No max-subtract.
                float e[4], d[4];
                #pragma unroll
                for (int k = 0; k < 4; ++k) { e[k] = __expf(lp[k]); }
                #pragma unroll
                for (int k = 0; k < 4; ++k) d[k] = dpp_xadd<DPP_ROR4>(e[k]);
                #pragma unroll
                for (int k = 0; k < 4; ++k) d[k] = dpp_xadd<DPP_ROR8>(d[k]);
                #pragma unroll
                for (int k = 0; k < 4; ++k) d[k] += __shfl_xor(d[k], 16);
                #pragma unroll
                for (int k = 0; k < 4; ++k) {
                    const float c = e[k] * __builtin_amdgcn_rcpf(d[k]);
                    #pragma unroll
                    for (int m = 0; m < 4; ++m) s[k][m] += c * u[k][m];
                }
            }
        }
        __syncthreads();
    }

    // ---- store block-partial s: partial[blk][b][j][m] (each owned once) ----
    const float sc = (MODE == 0) ? 0.125f : 1.0f;
    float* pp = partial + (size_t)blk * S_ELEMS;
    #pragma unroll
    for (int k = 0; k < 4; ++k) {
        float4 o;
        o.x = s[k][0] * sc; o.y = s[k][1] * sc;
        o.z = s[k][2] * sc; o.w = s[k][3] * sc;
        *(float4*)&pp[((bq + 16 * k) * JCAPS + j) * MDIM + mq * 4] = o;
    }
}

// Sum 256 partials -> s[b,j,m]; v = squash(s).
// OP 0: vsum = v (first pass, avoids memset)   OP 1: vsum += v   OP 2: out = v
template <int OP>
__global__ __launch_bounds__(256) void caps_reduce_kernel(
    const float* __restrict__ partial, float* __restrict__ vsum, float* __restrict__ out)
{
    __shared__ float sd[256];
    const int bo  = blockIdx.x;     // 0..127, each block covers 64 outputs
    const int tid = threadIdx.x;
    const int kg  = tid >> 6;       // 0..3  partial-group (64 partials each)
    const int tl  = tid & 63;       // output-within-block; lanes contiguous in t
    const int t   = bo * 64 + tl;   // global output index (= b*128 + j*16 + m)

    float a0 = 0.f, a1 = 0.f, a2 = 0.f, a3 = 0.f;
    const float* p = partial + (size_t)kg * 64 * S_ELEMS + t;
    #pragma unroll
    for (int k = 0; k < 64; k += 4) {
        a0 += p[(size_t)(k + 0) * S_ELEMS];
        a1 += p[(size_t)(k + 1) * S_ELEMS];
        a2 += p[(size_t)(k + 2) * S_ELEMS];
        a3 += p[(size_t)(k + 3) * S_ELEMS];
    }
    sd[tid] = (a0 + a1) + (a2 + a3);
    __syncthreads();

    if (tid < 64) {
        const float s = (sd[tid] + sd[64 + tid]) + (sd[128 + tid] + sd[192 + tid]);
        // squash: sn over the 16 m's of this (b,j) — lanes grouped by 16
        float sn = s * s;
        sn += __shfl_xor(sn, 1);
        sn += __shfl_xor(sn, 2);
        sn += __shfl_xor(sn, 4);
        sn += __shfl_xor(sn, 8);
        const float v = s * sqrtf(sn) / (1.f + sn);
        const int tt = bo * 64 + tid;
        if (OP == 2)      out[tt]   = v;
        else if (OP == 1) vsum[tt] += v;
        else              vsum[tt]  = v;
    }
}

extern "C" void kernel_launch(void* const* d_in, const int* in_sizes, int n_in,
                              void* d_out, int out_size, void* d_ws, size_t ws_size,
                              hipStream_t stream)
{
    const float* x = (const float*)d_in[0];   // [64, 8192, 8]
    const float* W = (const float*)d_in[1];   // [8192, 8, 8, 16]
    float* out = (float*)d_out;               // [64, 8, 16]

    float* partial = (float*)d_ws;                              // 256 * 8192 floats = 8 MB
    float* vsum    = partial + (size_t)NBLK * S_ELEMS;          // 8192 floats

    // pass 1: c uniform
    caps_pass_kernel<0><<<NBLK, 512, 0, stream>>>(x, W, vsum, partial);
    caps_reduce_kernel<0><<<128, 256, 0, stream>>>(partial, vsum, nullptr);  // vsum = v1
    // pass 2: logits = dot(v1, u_hat)
    caps_pass_kernel<1><<<NBLK, 512, 0, stream>>>(x, W, vsum, partial);
    caps_reduce_kernel<1><<<128, 256, 0, stream>>>(partial, vsum, nullptr);  // vsum = v1+v2
    // pass 3 (final): logits = dot(v1+v2, u_hat), output squash
    caps_pass_kernel<1><<<NBLK, 512, 0, stream>>>(x, W, vsum, partial);
    caps_reduce_kernel<2><<<128, 256, 0, stream>>>(partial, vsum, out);
}